// Round 4
// baseline (265.932 us; speedup 1.0000x reference)
//
#include <hip/hip_runtime.h>

#define NB 8
#define NC 256
#define NL 2048
#define SCALE 0.0625f   // C^-0.5 = 1/16

typedef __attribute__((ext_vector_type(8)))  __bf16 bf16x8;
typedef __attribute__((ext_vector_type(16))) float  f32x16;
typedef __attribute__((ext_vector_type(4)))  unsigned int u32x4;

// round-to-nearest-even fp32 -> bf16 bits
static __device__ __forceinline__ unsigned short f2b(float f) {
    unsigned int u = __builtin_bit_cast(unsigned int, f);
    u += 0x7fffu + ((u >> 16) & 1u);
    return (unsigned short)(u >> 16);
}
static __device__ __forceinline__ unsigned int pack2(float lo, float hi) {
    return (unsigned int)f2b(lo) | ((unsigned int)f2b(hi) << 16);
}

// Build two B-operand frags (k=h*8+j over 16 rows each) from a 32-row C-layout
// column held as 8 packed pairs pk[i] (rows {2i,2i+1} of the C row pattern).
// C rows per lane: {0..3,8..11,16..19,24..27}+4h; partner (lane^32) holds the rest.
static __device__ __forceinline__ void build_frags(
    const unsigned int pk[8], int h, u32x4& f0, u32x4& f1)
{
    unsigned int xc[8];
    #pragma unroll
    for (int i = 0; i < 8; ++i) xc[i] = (unsigned int)__shfl_xor((int)pk[i], 32, 64);
    f0[0] = h ? xc[2] : pk[0];  f0[1] = h ? xc[3] : pk[1];
    f0[2] = h ? pk[2] : xc[0];  f0[3] = h ? pk[3] : xc[1];
    f1[0] = h ? xc[6] : pk[4];  f1[1] = h ? xc[7] : pk[5];
    f1[2] = h ? pk[6] : xc[4];  f1[3] = h ? pk[7] : xc[5];
}

// ---------------------------------------------------------------------------
// wconv: W fp32 [o][c] -> WA frag-major bf16: frag(mat, ot, T) = A[m=o][k=c],
// lane = ot*32+(lane&31), elems c = T*16 + (lane>>5)*8 + j. grid 24, block 256.
// ---------------------------------------------------------------------------
__global__ void wconv_kernel(const float* __restrict__ Wq,
                             const float* __restrict__ Wk,
                             const float* __restrict__ Wv,
                             unsigned short* __restrict__ WA)
{
    const int mat = blockIdx.x >> 3;
    const int ot  = blockIdx.x & 7;
    const int t = threadIdx.x, w = t >> 6, lane = t & 63;
    const int ln31 = lane & 31, h = lane >> 5;
    const float* W = (mat == 0) ? Wq : (mat == 1) ? Wk : Wv;
    const int o = ot * 32 + ln31;
    #pragma unroll
    for (int tt = 0; tt < 4; ++tt) {
        const int T = w * 4 + tt;
        const int c = T * 16 + h * 8;
        float4 a = *(const float4*)&W[(size_t)o * NC + c];
        float4 b2 = *(const float4*)&W[(size_t)o * NC + c + 4];
        u32x4 fr = {pack2(a.x, a.y), pack2(a.z, a.w),
                    pack2(b2.x, b2.y), pack2(b2.z, b2.w)};
        *(u32x4*)&WA[(((size_t)(mat * 8 + ot)) * 16 + T) * 512 + lane * 8] = fr;
    }
}

// ---------------------------------------------------------------------------
// xprep: x fp32 [B][C][L] -> xB frag-major bf16: frag(b, lt32, T):
// lane = l-local, elems c = T*16 + h*8 + j.  grid (32,8), block 256.
// ---------------------------------------------------------------------------
__global__ __launch_bounds__(256, 2) void xprep_kernel(
    const float* __restrict__ x, unsigned short* __restrict__ xB)
{
    const int b = blockIdx.y, lt = blockIdx.x, l0 = lt * 64;
    const int t = threadIdx.x;
    __shared__ __align__(16) unsigned short XTr[64 * 264];  // [l][c], pitch 264

    #pragma unroll
    for (int p = 0; p < 16; ++p) {
        const int c = p * 16 + (t >> 4);
        const int l = (t & 15) * 4;
        float4 xv = *(const float4*)&x[((size_t)(b * NC + c)) * NL + l0 + l];
        XTr[(l + 0) * 264 + c] = f2b(xv.x);
        XTr[(l + 1) * 264 + c] = f2b(xv.y);
        XTr[(l + 2) * 264 + c] = f2b(xv.z);
        XTr[(l + 3) * 264 + c] = f2b(xv.w);
    }
    __syncthreads();
    const int w = t >> 6, lane = t & 63, ln31 = lane & 31, h = lane >> 5;
    #pragma unroll
    for (int s = 0; s < 8; ++s) {
        const int f = w * 8 + s;            // 0..31
        const int lg = f >> 4, T = f & 15;
        const int l = lg * 32 + ln31;
        u32x4 fr = *(const u32x4*)&XTr[l * 264 + T * 16 + h * 8];
        *(u32x4*)&xB[(((size_t)(b * 64 + lt * 2 + lg)) * 16 + T) * 512 + lane * 8] = fr;
    }
}

// ---------------------------------------------------------------------------
// qkv: pure frag-major MFMA GEMM, no LDS. grid 768 (b=raw&7, mat, lt64).
// q/k: D[o][l] = W·x;  v: D[l][o] = x·W (operands swapped).
// Outputs stored directly in attention's fragment layouts (qB, kA, vA).
// ---------------------------------------------------------------------------
__global__ __launch_bounds__(256, 2) void qkv_kernel(
    const unsigned short* __restrict__ xB,
    const unsigned short* __restrict__ WA,
    const float* __restrict__ bq, const float* __restrict__ bk,
    const float* __restrict__ bv,
    unsigned short* __restrict__ qB, unsigned short* __restrict__ kA,
    unsigned short* __restrict__ vA)
{
    const int raw = blockIdx.x;
    const int b   = raw & 7;
    const int rem = raw >> 3;
    const int mat = rem >> 5;          // 0=q 1=k 2=v
    const int lt  = rem & 31;          // 64-l tile
    const int t = threadIdx.x, w = t >> 6, lane = t & 63;
    const int ln31 = lane & 31, h = lane >> 5;
    const int og = w >> 1, lg = w & 1;
    const float* bias = (mat == 0) ? bq : (mat == 1) ? bk : bv;

    // x frags (lane = l): B-operand for q/k, A-operand for v — same frag.
    bf16x8 xf[16];
    {
        const size_t base = (((size_t)(b * 64 + lt * 2 + lg)) * 16) * 512 + lane * 8;
        #pragma unroll
        for (int T = 0; T < 16; ++T)
            xf[T] = __builtin_bit_cast(bf16x8, *(const u32x4*)&xB[base + T * 512]);
    }

    #pragma unroll
    for (int ot = 0; ot < 4; ++ot) {
        const int OT = og * 4 + ot;    // o-tile of 32
        f32x16 accA, accB;
        #pragma unroll
        for (int i = 0; i < 16; ++i) { accA[i] = 0.f; accB[i] = 0.f; }

        const size_t wbase = (((size_t)(mat * 8 + OT)) * 16) * 512 + lane * 8;
        #pragma unroll
        for (int T = 0; T < 16; ++T) {
            bf16x8 wf = __builtin_bit_cast(bf16x8, *(const u32x4*)&WA[wbase + T * 512]);
            if (mat < 2) {
                if (T & 1) accB = __builtin_amdgcn_mfma_f32_32x32x16_bf16(wf, xf[T], accB, 0, 0, 0);
                else       accA = __builtin_amdgcn_mfma_f32_32x32x16_bf16(wf, xf[T], accA, 0, 0, 0);
            } else {
                if (T & 1) accB = __builtin_amdgcn_mfma_f32_32x32x16_bf16(xf[T], wf, accB, 0, 0, 0);
                else       accA = __builtin_amdgcn_mfma_f32_32x32x16_bf16(xf[T], wf, accA, 0, 0, 0);
            }
        }

        float e[16];
        if (mat < 2) {
            // rows = o (pattern +4h), cols = l. bias indexed by row.
            #pragma unroll
            for (int g = 0; g < 4; ++g) {
                float4 bg = *(const float4*)&bias[OT * 32 + g * 8 + 4 * h];
                e[4 * g + 0] = accA[4 * g + 0] + accB[4 * g + 0] + bg.x;
                e[4 * g + 1] = accA[4 * g + 1] + accB[4 * g + 1] + bg.y;
                e[4 * g + 2] = accA[4 * g + 2] + accB[4 * g + 2] + bg.z;
                e[4 * g + 3] = accA[4 * g + 3] + accB[4 * g + 3] + bg.w;
            }
        } else {
            const float bvv = bias[OT * 32 + ln31];   // col = o = lane
            #pragma unroll
            for (int r = 0; r < 16; ++r) e[r] = accA[r] + accB[r] + bvv;
        }

        unsigned int pk[8];
        #pragma unroll
        for (int i = 0; i < 8; ++i) pk[i] = pack2(e[2 * i], e[2 * i + 1]);
        u32x4 f0, f1;
        build_frags(pk, h, f0, f1);

        if (mat < 2) {
            // frag(lt32 = lt*2+lg, T = OT*2 + {0,1}), lane = l
            unsigned short* dst = (mat == 0) ? qB : kA;
            const size_t o0 = (((size_t)(b * 64 + lt * 2 + lg)) * 16 + OT * 2) * 512 + lane * 8;
            *(u32x4*)&dst[o0] = f0;
            *(u32x4*)&dst[o0 + 512] = f1;
        } else {
            // vA frag(ct = OT, s = lt*4 + lg*2 + {0,1}), lane = c
            const size_t o0 = (((size_t)(b * 8 + OT)) * 128 + lt * 4 + lg * 2) * 512 + lane * 8;
            *(u32x4*)&vA[o0] = f0;
            *(u32x4*)&vA[o0 + 512] = f1;
        }
    }
}

// ---------------------------------------------------------------------------
// attn: barrier-free, LDS-free main loop. grid 256 (b=raw&7, lt64).
// 4 waves = (qg, kg): 32 queries x 32-key slice per wave; kg-partials are
// additive (un-normalized softmax) and combined in the epilogue via LDS.
// ---------------------------------------------------------------------------
__global__ __launch_bounds__(256, 1) void attn_kernel(
    const unsigned short* __restrict__ qB,
    const unsigned short* __restrict__ kA,
    const unsigned short* __restrict__ vA,
    const float* __restrict__ x,
    float* __restrict__ out)
{
    const int raw = blockIdx.x;
    const int b  = raw & 7;
    const int lt = raw >> 3;
    const int l0 = lt * 64;
    const int t = threadIdx.x, w = t >> 6, lane = t & 63;
    const int ln31 = lane & 31, h = lane >> 5;
    const int qg = w & 1, kg = w >> 1;

    __shared__ float ctxbuf[2][256][32];   // 64 KB: [qg][c][q]
    __shared__ float denomL[64];

    // Q B-frags resident (lane = q)
    bf16x8 qf[16];
    {
        const size_t qbase = (((size_t)(b * 64 + lt * 2 + qg)) * 16) * 512 + lane * 8;
        #pragma unroll
        for (int T = 0; T < 16; ++T)
            qf[T] = __builtin_bit_cast(bf16x8, *(const u32x4*)&qB[qbase + T * 512]);
    }

    f32x16 ctx[8];
    #pragma unroll
    for (int ct = 0; ct < 8; ++ct)
        #pragma unroll
        for (int i = 0; i < 16; ++i) ctx[ct][i] = 0.f;
    float dacc = 0.f;

    for (int mt = 0; mt < 32; ++mt) {
        const int kt = mt * 2 + kg;         // 32-key slice index
        // K A-frags (lane = key): issue first
        u32x4 kf[16];
        {
            const size_t kbase = (((size_t)(b * 64 + kt)) * 16) * 512 + lane * 8;
            #pragma unroll
            for (int T = 0; T < 16; ++T) kf[T] = *(const u32x4*)&kA[kbase + T * 512];
        }
        // V A-frags (lane = c): arrive while QK computes
        u32x4 vf[16];
        {
            const size_t vbase = (((size_t)(b * 8)) * 128 + mt * 4 + kg * 2) * 512 + lane * 8;
            #pragma unroll
            for (int ct = 0; ct < 8; ++ct) {
                vf[ct * 2 + 0] = *(const u32x4*)&vA[vbase + (size_t)ct * 65536];
                vf[ct * 2 + 1] = *(const u32x4*)&vA[vbase + (size_t)ct * 65536 + 512];
            }
        }

        // S^T[key][q] = K·Q^T over c (two interleaved chains)
        f32x16 s0, s1;
        #pragma unroll
        for (int i = 0; i < 16; ++i) { s0[i] = 0.f; s1[i] = 0.f; }
        #pragma unroll
        for (int T = 0; T < 16; T += 2) {
            s0 = __builtin_amdgcn_mfma_f32_32x32x16_bf16(
                     __builtin_bit_cast(bf16x8, kf[T]), qf[T], s0, 0, 0, 0);
            s1 = __builtin_amdgcn_mfma_f32_32x32x16_bf16(
                     __builtin_bit_cast(bf16x8, kf[T + 1]), qf[T + 1], s1, 0, 0, 0);
        }

        // exp (no max-sub), per-q denominator partial
        float e[16], ds = 0.f;
        #pragma unroll
        for (int r = 0; r < 16; ++r) {
            e[r] = __expf((s0[r] + s1[r]) * SCALE);
            ds += e[r];
        }
        ds += __shfl_xor(ds, 32, 64);
        dacc += ds;

        // C-layout -> B-operand frags, in-register
        unsigned int pk[8];
        #pragma unroll
        for (int i = 0; i < 8; ++i) pk[i] = pack2(e[2 * i], e[2 * i + 1]);
        u32x4 pf0, pf1;
        build_frags(pk, h, pf0, pf1);
        bf16x8 p0 = __builtin_bit_cast(bf16x8, pf0);
        bf16x8 p1 = __builtin_bit_cast(bf16x8, pf1);

        // ctx[c][q] += V·P
        #pragma unroll
        for (int ct = 0; ct < 8; ++ct) {
            ctx[ct] = __builtin_amdgcn_mfma_f32_32x32x16_bf16(
                          __builtin_bit_cast(bf16x8, vf[ct * 2 + 0]), p0, ctx[ct], 0, 0, 0);
            ctx[ct] = __builtin_amdgcn_mfma_f32_32x32x16_bf16(
                          __builtin_bit_cast(bf16x8, vf[ct * 2 + 1]), p1, ctx[ct], 0, 0, 0);
        }
    }

    // ---- epilogue: combine kg halves, normalize, residual, store ----
    if (kg == 1) {
        #pragma unroll
        for (int ct = 0; ct < 8; ++ct)
            #pragma unroll
            for (int r = 0; r < 16; ++r) {
                const int c = ct * 32 + (r & 3) + 8 * (r >> 2) + 4 * h;
                ctxbuf[qg][c][ln31] = ctx[ct][r];
            }
        if (lane < 32) denomL[qg * 32 + ln31] = dacc;
    }
    __syncthreads();
    if (kg == 0) {
        const float rinv = 1.0f / (denomL[qg * 32 + ln31] + dacc);
        #pragma unroll
        for (int ct = 0; ct < 8; ++ct)
            #pragma unroll
            for (int r = 0; r < 16; ++r) {
                const int c = ct * 32 + (r & 3) + 8 * (r >> 2) + 4 * h;
                ctxbuf[qg][c][ln31] = (ctx[ct][r] + ctxbuf[qg][c][ln31]) * rinv;
            }
    }
    __syncthreads();

    const int cr = t >> 4;
    const int lgp = (t & 15) * 4;
    const int qg2 = lgp >> 5, q4 = lgp & 31;
    #pragma unroll
    for (int p = 0; p < 16; ++p) {
        const int c = p * 16 + cr;
        const size_t idx = ((size_t)(b * NC + c)) * NL + l0 + lgp;
        float4 xv = *(const float4*)&x[idx];
        float4 cv = *(const float4*)&ctxbuf[qg2][c][q4];
        float4 o = make_float4(cv.x + xv.x, cv.y + xv.y, cv.z + xv.z, cv.w + xv.w);
        *(float4*)&out[idx] = o;
    }
}

// ---------------------------------------------------------------------------
extern "C" void kernel_launch(void* const* d_in, const int* in_sizes, int n_in,
                              void* d_out, int out_size, void* d_ws, size_t ws_size,
                              hipStream_t stream) {
    const float* x  = (const float*)d_in[0];
    const float* Wq = (const float*)d_in[1];
    const float* bq = (const float*)d_in[2];
    const float* Wk = (const float*)d_in[3];
    const float* bk = (const float*)d_in[4];
    const float* Wv = (const float*)d_in[5];
    const float* bv = (const float*)d_in[6];
    float* out = (float*)d_out;

    const size_t plane = (size_t)NB * NC * NL;       // 4.19M elems
    unsigned short* qB = (unsigned short*)d_ws;
    unsigned short* kA = qB + plane;
    unsigned short* vA = kA + plane;
    unsigned short* xB = vA + plane;
    unsigned short* WA = xB + plane;                 // 3*65536 elems

    wconv_kernel<<<24, 256, 0, stream>>>(Wq, Wk, Wv, WA);

    dim3 gx(NL / 64, NB);                            // (32, 8)
    xprep_kernel<<<gx, 256, 0, stream>>>(x, xB);

    qkv_kernel<<<768, 256, 0, stream>>>(xB, WA, bq, bk, bv, qB, kA, vA);

    attn_kernel<<<256, 256, 0, stream>>>(qB, kA, vA, x, out);
}

// Round 5
// 165.341 us; speedup vs baseline: 1.6084x; 1.6084x over previous
//
#include <hip/hip_runtime.h>

#define NB 8
#define NC 256
#define NL 2048
#define SCALE 0.0625f   // C^-0.5 = 1/16

typedef __attribute__((ext_vector_type(8))) __bf16 bf16x8;
typedef __attribute__((ext_vector_type(4))) float f32x4;
typedef __attribute__((ext_vector_type(4))) unsigned int u32x4;
typedef __attribute__((ext_vector_type(4))) unsigned short u16x4;
typedef __attribute__((ext_vector_type(8))) unsigned short u16x8;

// round-to-nearest-even fp32 -> bf16 bits
static __device__ __forceinline__ unsigned short f2b(float f) {
    unsigned int u = __builtin_bit_cast(unsigned int, f);
    u += 0x7fffu + ((u >> 16) & 1u);
    return (unsigned short)(u >> 16);
}

// ---------------------------------------------------------------------------
// Prep A: Wq/Wk/Wv fp32 -> bf16, concatenated [3][256][256].
// ---------------------------------------------------------------------------
__global__ void wconv_kernel(const float* __restrict__ Wq,
                             const float* __restrict__ Wk,
                             const float* __restrict__ Wv,
                             unsigned short* __restrict__ Wbf)
{
    const int base = (blockIdx.x * 256 + threadIdx.x) * 4;
    const int mat  = base >> 16;
    const int off  = base & 65535;
    const float* W = (mat == 0) ? Wq : (mat == 1) ? Wk : Wv;
    float4 w = *(const float4*)&W[off];
    u16x4 p = {f2b(w.x), f2b(w.y), f2b(w.z), f2b(w.w)};
    *(u16x4*)&Wbf[base] = p;
}

// ---------------------------------------------------------------------------
// Prep B: x [B][C][L] fp32 -> xT [B][L][C] bf16 (transpose via LDS).
// ---------------------------------------------------------------------------
__global__ __launch_bounds__(256, 2) void xprep_kernel(
    const float* __restrict__ x, unsigned short* __restrict__ xT)
{
    const int b  = blockIdx.z;
    const int c0 = blockIdx.y * 64;
    const int l0 = blockIdx.x * 64;
    const int t  = threadIdx.x;

    __shared__ unsigned short Tr[64][68];

    #pragma unroll
    for (int p = 0; p < 4; ++p) {
        const int c  = p * 16 + (t >> 4);
        const int lg = t & 15;
        float4 xv = *(const float4*)&x[((size_t)(b * NC + c0 + c)) * NL + l0 + lg * 4];
        u16x4 pk = {f2b(xv.x), f2b(xv.y), f2b(xv.z), f2b(xv.w)};
        *(u16x4*)&Tr[c][lg * 4] = pk;
    }
    __syncthreads();
    #pragma unroll
    for (int j = 0; j < 2; ++j) {
        const int chunk = t + 256 * j;      // 0..511
        const int l  = chunk >> 3;
        const int ck = chunk & 7;
        u16x8 o;
        #pragma unroll
        for (int i = 0; i < 8; ++i) o[i] = Tr[ck * 8 + i][l];
        *(u16x8*)&xT[((size_t)(b * NL + l0 + l)) * NC + c0 + ck * 8] = o;
    }
}

// ---------------------------------------------------------------------------
// Kernel 1: QKV projection via MFMA (verbatim from R3 verified state).
// ---------------------------------------------------------------------------
__global__ __launch_bounds__(256, 2) void qkv_mfma(
    const unsigned short* __restrict__ xT,
    const unsigned short* __restrict__ Wbf,
    const float* __restrict__ bq, const float* __restrict__ bk,
    const float* __restrict__ bv,
    unsigned short* __restrict__ qT, unsigned short* __restrict__ kT,
    unsigned short* __restrict__ vo)
{
    const int raw = blockIdx.x;
    const int b   = raw & 7;          // XCD-pinned batch
    const int rem = raw >> 3;         // 0..95
    const int mat = rem >> 5;         // 0..2
    const int lt0 = (rem & 31) * 64;
    const int t    = threadIdx.x;
    const int w    = t >> 6;
    const int lane = t & 63;
    const int ln15 = lane & 15;
    const int quad = lane >> 4;

    __shared__ __align__(16) unsigned short XT[64 * 256];  // [l][c] swz, 32 KB
    __shared__ __align__(16) unsigned short WC[256 * 64];  // [o][c-chunk] swz, 32 KB

    const unsigned short* Wm = Wbf + mat * 65536;
    const float* bias = (mat == 0) ? bq : (mat == 1) ? bk : bv;

    float bvals[4][4];
    #pragma unroll
    for (int ot = 0; ot < 4; ++ot)
        #pragma unroll
        for (int r = 0; r < 4; ++r)
            bvals[ot][r] = bias[w * 64 + ot * 16 + quad * 4 + r];

    #pragma unroll
    for (int s = 0; s < 8; ++s) {
        const int il = w * 8 + s;
        const int n  = il * 2 + (lane >> 5);
        const int p  = lane & 31;
        const int g  = p ^ (n & 15);
        const unsigned short* gp = &xT[((size_t)(b * NL + lt0 + n)) * NC + g * 8];
        __builtin_amdgcn_global_load_lds(
            (const __attribute__((address_space(1))) unsigned int*)gp,
            (__attribute__((address_space(3))) unsigned int*)&XT[il * 512],
            16, 0, 0);
    }

    f32x4 acc[4][4];
    #pragma unroll
    for (int i = 0; i < 4; ++i)
        #pragma unroll
        for (int j = 0; j < 4; ++j) acc[i][j] = f32x4{0.f, 0.f, 0.f, 0.f};

    for (int k0 = 0; k0 < 4; ++k0) {
        if (k0) __syncthreads();
        #pragma unroll
        for (int s = 0; s < 8; ++s) {
            const int il = w * 8 + s;
            const int o  = il * 8 + (lane >> 3);
            const int p  = lane & 7;
            const int g  = p ^ (o & 7);
            const unsigned short* gp = &Wm[(size_t)o * NC + k0 * 64 + g * 8];
            __builtin_amdgcn_global_load_lds(
                (const __attribute__((address_space(1))) unsigned int*)gp,
                (__attribute__((address_space(3))) unsigned int*)&WC[il * 512],
                16, 0, 0);
        }
        __syncthreads();

        #pragma unroll
        for (int ks = 0; ks < 2; ++ks) {
            bf16x8 xf[4];
            #pragma unroll
            for (int lt = 0; lt < 4; ++lt) {
                const int l  = lt * 16 + ln15;
                const int kc = k0 * 8 + ks * 4 + quad;
                const int pp = kc ^ (l & 15);
                xf[lt] = __builtin_bit_cast(bf16x8, *(const u32x4*)&XT[l * 256 + pp * 8]);
            }
            #pragma unroll
            for (int ot = 0; ot < 4; ++ot) {
                const int o  = w * 64 + ot * 16 + ln15;
                const int pp = (ks * 4 + quad) ^ (o & 7);
                bf16x8 wf = __builtin_bit_cast(bf16x8, *(const u32x4*)&WC[o * 64 + pp * 8]);
                #pragma unroll
                for (int lt = 0; lt < 4; ++lt)
                    acc[ot][lt] = __builtin_amdgcn_mfma_f32_16x16x32_bf16(
                                      wf, xf[lt], acc[ot][lt], 0, 0, 0);
            }
        }
    }

    if (mat < 2) {
        unsigned short* out = (mat == 0) ? qT : kT;
        #pragma unroll
        for (int ot = 0; ot < 4; ++ot) {
            const int o_base = w * 64 + ot * 16 + quad * 4;
            #pragma unroll
            for (int lt = 0; lt < 4; ++lt) {
                const int l = lt0 + lt * 16 + ln15;
                u16x4 pk;
                #pragma unroll
                for (int r = 0; r < 4; ++r)
                    pk[r] = f2b(acc[ot][lt][r] + bvals[ot][r]);
                *(u16x4*)&out[((size_t)(b * NL + l)) * NC + o_base] = pk;
            }
        }
    } else {
        #pragma unroll
        for (int ot = 0; ot < 4; ++ot)
            #pragma unroll
            for (int lt = 0; lt < 4; ++lt) {
                const int l = lt0 + lt * 16 + ln15;
                #pragma unroll
                for (int r = 0; r < 4; ++r) {
                    const int o = w * 64 + ot * 16 + quad * 4 + r;
                    vo[((size_t)(b * NC + o)) * NL + l] = f2b(acc[ot][lt][r] + bvals[ot][r]);
                }
            }
    }
}

// ---------------------------------------------------------------------------
// Kernel 2: MFMA flash attention + residual. grid 256 (b=raw&7, lt64),
// block 512 = 8 waves (qg 0..3 x kg 0..1). Double-buffered K/V staging,
// ONE barrier per key-tile; loads for tile mt+1 fly during compute of mt.
// kg halves hold additive partials (un-normalized softmax), combined in
// the epilogue via LDS (layout verified in R4).
// ---------------------------------------------------------------------------
__global__ __launch_bounds__(512, 1) void attn_kernel(
    const unsigned short* __restrict__ qT,
    const unsigned short* __restrict__ kT,
    const unsigned short* __restrict__ v,
    const float* __restrict__ x,
    float* __restrict__ out)
{
    const int raw  = blockIdx.x;
    const int b    = raw & 7;         // XCD-pinned batch
    const int l0   = (raw >> 3) * 64;
    const int t    = threadIdx.x;
    const int w    = t >> 6;
    const int lane = t & 63;
    const int ln15 = lane & 15;
    const int quad = lane >> 4;
    const int qg   = w & 3;           // query group (16 rows)
    const int kg   = w >> 2;          // key half (32 keys)

    __shared__ __align__(16) char smem[139776];
    unsigned short* Kb0 = (unsigned short*)smem;             // 32 KB
    unsigned short* Kb1 = (unsigned short*)(smem + 32768);   // 32 KB
    unsigned short* Vb0 = (unsigned short*)(smem + 65536);   // 32 KB
    unsigned short* Vb1 = (unsigned short*)(smem + 98304);   // 32 KB
    unsigned short* Plds = (unsigned short*)(smem + 131072); //  8 KB
    float* denomP = (float*)(smem + 139264);                 // 2*64 f32
    float (*ctxbuf)[68] = (float(*)[68])smem;                // epilogue alias

    // ---- Q fragments resident: rows l0 + qg*16 + ln15 ----
    bf16x8 qf[8];
    {
        const size_t qrow = ((size_t)b * NL + l0 + qg * 16 + ln15) * NC;
        #pragma unroll
        for (int kt = 0; kt < 8; ++kt)
            qf[kt] = __builtin_bit_cast(bf16x8,
                        *(const u32x4*)&qT[qrow + kt * 32 + quad * 8]);
    }

    f32x4 ctx[16];
    #pragma unroll
    for (int i = 0; i < 16; ++i) ctx[i] = f32x4{0.f, 0.f, 0.f, 0.f};
    float dacc[4] = {0.f, 0.f, 0.f, 0.f};

    auto stage = [&](int mt, unsigned short* Kd, unsigned short* Vd) {
        const int m0 = mt * 64;
        #pragma unroll
        for (int s = 0; s < 4; ++s) {
            const int il = w * 4 + s;
            const int n  = il * 2 + (lane >> 5);
            const int g  = (lane & 31) ^ (n & 15);
            const unsigned short* gp = &kT[((size_t)b * NL + m0 + n) * NC + g * 8];
            __builtin_amdgcn_global_load_lds(
                (const __attribute__((address_space(1))) unsigned int*)gp,
                (__attribute__((address_space(3))) unsigned int*)&Kd[il * 512],
                16, 0, 0);
        }
        #pragma unroll
        for (int s = 0; s < 4; ++s) {
            const int il = w * 4 + s;
            const int c  = il * 8 + (lane >> 3);
            const int g  = (lane & 7) ^ (c & 7);
            const unsigned short* gp = &v[((size_t)(b * NC + c)) * NL + m0 + g * 8];
            __builtin_amdgcn_global_load_lds(
                (const __attribute__((address_space(1))) unsigned int*)gp,
                (__attribute__((address_space(3))) unsigned int*)&Vd[il * 512],
                16, 0, 0);
        }
    };

    stage(0, Kb0, Vb0);
    __syncthreads();   // buf0 ready

    for (int mt = 0; mt < 32; ++mt) {
        // prefetch next tile into the other buffer (overlaps compute below)
        if (mt < 31) {
            if (mt & 1) stage(mt + 1, Kb0, Vb0);
            else        stage(mt + 1, Kb1, Vb1);
        }
        const unsigned short* Kd = (mt & 1) ? Kb1 : Kb0;
        const unsigned short* Vd = (mt & 1) ? Vb1 : Vb0;

        // ---- S = Q^T K (this wave: 16 q x 32 keys of half kg) ----
        f32x4 sacc[2];
        sacc[0] = f32x4{0.f, 0.f, 0.f, 0.f};
        sacc[1] = f32x4{0.f, 0.f, 0.f, 0.f};
        #pragma unroll
        for (int nt = 0; nt < 2; ++nt) {
            const int n = kg * 32 + nt * 16 + ln15;
            #pragma unroll
            for (int kt = 0; kt < 8; ++kt) {
                const int p = (kt * 4 + quad) ^ ln15;
                bf16x8 bf = __builtin_bit_cast(bf16x8,
                              *(const u32x4*)&Kd[n * 256 + p * 8]);
                sacc[nt] = __builtin_amdgcn_mfma_f32_16x16x32_bf16(
                               qf[kt], bf, sacc[nt], 0, 0, 0);
            }
        }

        // ---- exp (no max-sub), partial row sums, P -> LDS (wave-local) ----
        float rs[4] = {0.f, 0.f, 0.f, 0.f};
        #pragma unroll
        for (int nt = 0; nt < 2; ++nt) {
            #pragma unroll
            for (int r = 0; r < 4; ++r) {
                float e = __expf(sacc[nt][r] * SCALE);
                rs[r] += e;
                const int ip = qg * 16 + quad * 4 + r;
                const int j  = kg * 32 + nt * 16 + ln15;
                const int pc = (j >> 3) ^ (ip & 7);
                Plds[ip * 64 + pc * 8 + (j & 7)] = f2b(e);
            }
        }
        #pragma unroll
        for (int r = 0; r < 4; ++r) {
            rs[r] += __shfl_xor(rs[r], 1, 64);
            rs[r] += __shfl_xor(rs[r], 2, 64);
            rs[r] += __shfl_xor(rs[r], 4, 64);
            rs[r] += __shfl_xor(rs[r], 8, 64);
            dacc[r] += rs[r];
        }

        // ---- PV: ctx[q][c] partial over this wave's 32 j ----
        bf16x8 pf;
        {
            const int m = qg * 16 + ln15;
            const int p = (kg * 4 + quad) ^ (m & 7);
            pf = __builtin_bit_cast(bf16x8, *(const u32x4*)&Plds[m * 64 + p * 8]);
        }
        #pragma unroll
        for (int ct = 0; ct < 16; ++ct) {
            const int c = ct * 16 + ln15;
            const int p = (kg * 4 + quad) ^ (c & 7);
            bf16x8 vb = __builtin_bit_cast(bf16x8,
                          *(const u32x4*)&Vd[c * 64 + p * 8]);
            ctx[ct] = __builtin_amdgcn_mfma_f32_16x16x32_bf16(
                          pf, vb, ctx[ct], 0, 0, 0);
        }

        __syncthreads();   // drains prefetch vmcnt + guards buffer reuse
    }

    // ---- epilogue: combine kg halves, normalize, residual, store ----
    if (kg == 1) {
        #pragma unroll
        for (int ct = 0; ct < 16; ++ct) {
            const int c = ct * 16 + ln15;
            #pragma unroll
            for (int r = 0; r < 4; ++r)
                ctxbuf[c][qg * 16 + quad * 4 + r] = ctx[ct][r];
        }
    }
    if (ln15 == 0) {
        #pragma unroll
        for (int r = 0; r < 4; ++r)
            denomP[kg * 64 + qg * 16 + quad * 4 + r] = dacc[r];
    }
    __syncthreads();
    if (kg == 0) {
        float rinv[4];
        #pragma unroll
        for (int r = 0; r < 4; ++r) {
            const int ql = qg * 16 + quad * 4 + r;
            rinv[r] = 1.0f / (denomP[ql] + denomP[64 + ql]);
        }
        #pragma unroll
        for (int ct = 0; ct < 16; ++ct) {
            const int c = ct * 16 + ln15;
            #pragma unroll
            for (int r = 0; r < 4; ++r) {
                const int ql = qg * 16 + quad * 4 + r;
                ctxbuf[c][ql] = (ctx[ct][r] + ctxbuf[c][ql]) * rinv[r];
            }
        }
    }
    __syncthreads();

    #pragma unroll
    for (int p = 0; p < 8; ++p) {
        const int f  = t + 512 * p;       // 0..4095
        const int c  = f >> 4;
        const int lg = (f & 15) * 4;
        const size_t idx = ((size_t)(b * NC + c)) * NL + l0 + lg;
        float4 xv = *(const float4*)&x[idx];
        float4 cv = *(const float4*)&ctxbuf[c][lg];
        float4 o = make_float4(cv.x + xv.x, cv.y + xv.y, cv.z + xv.z, cv.w + xv.w);
        *(float4*)&out[idx] = o;
    }
}

// ---------------------------------------------------------------------------
extern "C" void kernel_launch(void* const* d_in, const int* in_sizes, int n_in,
                              void* d_out, int out_size, void* d_ws, size_t ws_size,
                              hipStream_t stream) {
    const float* x  = (const float*)d_in[0];
    const float* Wq = (const float*)d_in[1];
    const float* bq = (const float*)d_in[2];
    const float* Wk = (const float*)d_in[3];
    const float* bk = (const float*)d_in[4];
    const float* Wv = (const float*)d_in[5];
    const float* bv = (const float*)d_in[6];
    float* out = (float*)d_out;

    const size_t plane = (size_t)NB * NC * NL;       // 4.19M elems
    unsigned short* qT  = (unsigned short*)d_ws;
    unsigned short* kT  = qT + plane;
    unsigned short* v   = kT + plane;
    unsigned short* xT  = v + plane;
    unsigned short* Wbf = xT + plane;                // 3*65536 elems

    wconv_kernel<<<192, 256, 0, stream>>>(Wq, Wk, Wv, Wbf);

    dim3 gx(NL / 64, NC / 64, NB);                   // (32, 4, 8)
    xprep_kernel<<<gx, 256, 0, stream>>>(x, xT);

    qkv_mfma<<<768, 256, 0, stream>>>(xT, Wbf, bq, bk, bv, qT, kT, v);

    attn_kernel<<<256, 512, 0, stream>>>(qT, kT, v, x, out);
}